// Round 16
// baseline (131.694 us; speedup 1.0000x reference)
//
#include <hip/hip_runtime.h>
#include <math.h>

// flash-decode, GQA paged KV. R=4, B=16, Hq=32, Hk=8 (G=4), D=128, P=8192,
// PAGE=1, M=2048. Storage (r7): q/k/v FLOAT32; lens/bt int32; out f32.
//
// Round 16: whole-page reads. Block = (r, b, 128-token window); its 4 waves
// cover all 8 hk (wave = hkg-half x token-half; lane = hk-slice x dim-slice).
// Each wave-load is 2 KB contiguous (4 hk rows of one page); sibling wave
// reads the other 2 KB -> full 4 KB page granule vs 512 B before (r8-r15
// all capped at ~2 TB/s with 512 B random reads). Softmax sequential per
// lane (no slot merges); token-halves merge once via LDS.

typedef float f32x4 __attribute__((ext_vector_type(4)));

#define R_ 4
#define B_ 16
#define HQ_ 32
#define HK_ 8
#define G_ 4
#define D_ 128
#define P_ 8192
#define M_ 2048
#define HKD (HK_ * D_)
#define NWIN 16   // 128-token windows per (r,b)
#define WTOK 128
#define SC2 (0.08838834764831845f * 1.4426950408889634f)  // scale * log2(e)
#define MNEG (-1.0e30f)

__device__ __forceinline__ void load8b(const char* __restrict__ base,
                                       unsigned boff, float o[8]) {
  const f32x4* p = (const f32x4*)(base + boff);
  f32x4 a = p[0];
  f32x4 b = p[1];
#pragma unroll
  for (int j = 0; j < 4; ++j) { o[j] = a[j]; o[4 + j] = b[j]; }
}

__device__ __forceinline__ int clampP(int p) {
  return p < 0 ? 0 : (p >= P_ ? P_ - 1 : p);
}

// ---------------- kernel 1: block = (r,b,window); all 8 hk ----------------
__global__ __launch_bounds__(256) void fd_partial(
    const float* __restrict__ q, const float* __restrict__ kc,
    const float* __restrict__ vc, const int* __restrict__ lens,
    const int* __restrict__ bt, float* __restrict__ ws_m,
    float* __restrict__ ws_l, float* __restrict__ ws_o) {
  const int rec = blockIdx.x;      // (r*B+b)*NWIN + s
  const int s = rec & (NWIN - 1);
  const int rb = rec >> 4;         // r*B + b
  const int b = rb & (B_ - 1);
  const int r = rb >> 4;

  const int tid = threadIdx.x;
  const int lane = tid & 63;
  const int w = tid >> 6;
  const int hkg = w & 1;   // hk group: 0 -> hk 0-3, 1 -> hk 4-7
  const int th = w >> 1;   // token half: 0 -> [0,64), 1 -> [64,128)
  const int hkl = lane >> 4;
  const int hk = hkg * 4 + hkl;
  const int ds = (lane & 15) * 8;
  // byte offset within a 4 KB page for this lane's (hk, dim-slice)
  const unsigned hko = ((unsigned)hk << 9) + (unsigned)ds * 4u;

  int kvlen = lens[rb];
  if (kvlen < 0) kvlen = 0;
  if (kvlen > M_) kvlen = M_;
  const int base = s * WTOK;
  if (base >= kvlen) {  // whole block inactive (uniform): sentinel + exit
    if (tid < 32) ws_m[rec * 32 + tid] = MNEG;
    return;
  }
  const int t1 = (base + WTOK < kvlen) ? base + WTOK : kvlen;
  const int w0 = base + th * 64;
  int w1 = w0 + 64;
  if (w1 > t1) w1 = t1;

  // q fragments: 4 g-heads of this lane's hk, pre-scaled (log2 domain)
  float qf[G_][8];
  {
    const float* qp = q + ((size_t)b * HQ_ + hk * G_) * D_ + ds;
#pragma unroll
    for (int g = 0; g < G_; ++g) {
      const f32x4* p = (const f32x4*)(qp + g * D_);
      f32x4 a = p[0], c = p[1];
#pragma unroll
      for (int j = 0; j < 4; ++j) {
        qf[g][j] = a[j] * SC2;
        qf[g][4 + j] = c[j] * SC2;
      }
    }
  }

  const int* btrow = bt + rb * M_;
  const char* kbase = (const char*)(kc + (size_t)r * P_ * HKD);
  const char* vbase = (const char*)(vc + (size_t)r * P_ * HKD);

  float m[G_], l[G_], acc[G_][8];
#pragma unroll
  for (int g = 0; g < G_; ++g) {
    m[g] = MNEG;
    l[g] = 0.f;
#pragma unroll
    for (int j = 0; j < 8; ++j) acc[g][j] = 0.f;
  }

  const int nIt = (w1 - w0 + 3) >> 2;  // 0 if this wave's half is empty
  if (nIt > 0) {
    int4 pgN = *(const int4*)(btrow + w0);  // wave-uniform
#pragma unroll 1
    for (int i = 0; i < nIt; ++i) {
      const int4 pg = pgN;
      if (i + 1 < nIt) pgN = *(const int4*)(btrow + w0 + (i + 1) * 4);
      const unsigned o0 = ((unsigned)clampP(pg.x) << 12) + hko;
      const unsigned o1 = ((unsigned)clampP(pg.y) << 12) + hko;
      const unsigned o2 = ((unsigned)clampP(pg.z) << 12) + hko;
      const unsigned o3 = ((unsigned)clampP(pg.w) << 12) + hko;

      float k0[8], k1[8], k2[8], k3[8], v0[8], v1[8], v2[8], v3[8];
      load8b(kbase, o0, k0);
      load8b(kbase, o1, k1);
      load8b(kbase, o2, k2);
      load8b(kbase, o3, k3);
      load8b(vbase, o0, v0);
      load8b(vbase, o1, v1);
      load8b(vbase, o2, v2);
      load8b(vbase, o3, v3);

      float d0[G_], d1[G_], d2[G_], d3[G_];
#pragma unroll
      for (int g = 0; g < G_; ++g) {
        float a0 = 0.f, a1 = 0.f, a2 = 0.f, a3 = 0.f;
#pragma unroll
        for (int j = 0; j < 8; ++j) {
          a0 += qf[g][j] * k0[j];
          a1 += qf[g][j] * k1[j];
          a2 += qf[g][j] * k2[j];
          a3 += qf[g][j] * k3[j];
        }
        d0[g] = a0; d1[g] = a1; d2[g] = a2; d3[g] = a3;
      }
#pragma unroll
      for (int msk = 1; msk <= 8; msk <<= 1) {
#pragma unroll
        for (int g = 0; g < G_; ++g) {
          d0[g] += __shfl_xor(d0[g], msk);
          d1[g] += __shfl_xor(d1[g], msk);
          d2[g] += __shfl_xor(d2[g], msk);
          d3[g] += __shfl_xor(d3[g], msk);
        }
      }

      const int tb = w0 + i * 4;  // wave-uniform validity
      const bool va0 = tb < w1;
      const bool va1 = tb + 1 < w1;
      const bool va2 = tb + 2 < w1;
      const bool va3 = tb + 3 < w1;
#pragma unroll
      for (int g = 0; g < G_; ++g) {
        const float s0 = va0 ? d0[g] : -INFINITY;
        const float s1 = va1 ? d1[g] : -INFINITY;
        const float s2 = va2 ? d2[g] : -INFINITY;
        const float s3 = va3 ? d3[g] : -INFINITY;
        const float mt = fmaxf(fmaxf(s0, s1), fmaxf(s2, s3));
        const float mn = fmaxf(m[g], mt);   // finite (>= MNEG)
        const float sc = exp2f(m[g] - mn);  // branchless
        const float p0 = exp2f(s0 - mn);    // -inf -> 0
        const float p1 = exp2f(s1 - mn);
        const float p2 = exp2f(s2 - mn);
        const float p3 = exp2f(s3 - mn);
        m[g] = mn;
        l[g] = l[g] * sc + (p0 + p1) + (p2 + p3);
#pragma unroll
        for (int j = 0; j < 8; ++j)
          acc[g][j] = acc[g][j] * sc + p0 * v0[j] + p1 * v1[j] + p2 * v2[j] +
                      p3 * v3[j];
      }
    }
  }

  // merge the two token-halves via LDS (one merge per block)
  __shared__ float sm[4][4][G_], sl[4][4][G_], so[4][4][G_][D_];
  if ((lane & 15) == 0) {
#pragma unroll
    for (int g = 0; g < G_; ++g) {
      sm[w][hkl][g] = m[g];
      sl[w][hkl][g] = l[g];
    }
  }
#pragma unroll
  for (int g = 0; g < G_; ++g) {
#pragma unroll
    for (int j = 0; j < 8; ++j) so[w][hkl][g][ds + j] = acc[g][j];
  }
  __syncthreads();

  // tid -> (hk8, g, 16-dim chunk); combine th=0 (w=hkg) and th=1 (w=2+hkg)
  const int hk8 = tid >> 5;
  const int g2 = (tid >> 3) & 3;
  const int dp = (tid & 7) * 16;
  const int hg = hk8 >> 2;
  const int hl = hk8 & 3;
  const float m0 = sm[hg][hl][g2];
  const float m1 = sm[2 + hg][hl][g2];
  const float mf = fmaxf(m0, m1);
  const float wt0 = exp2f(m0 - mf);
  const float wt1 = exp2f(m1 - mf);
  const float lf = wt0 * sl[hg][hl][g2] + wt1 * sl[2 + hg][hl][g2];
  const int row = rec * 32 + hk8 * G_ + g2;
#pragma unroll
  for (int j = 0; j < 16; ++j)
    ws_o[(size_t)row * D_ + dp + j] =
        wt0 * so[hg][hl][g2][dp + j] + wt1 * so[2 + hg][hl][g2][dp + j];
  if ((tid & 7) == 0) {
    ws_m[row] = mf;  // log2-domain
    ws_l[row] = lf;
  }
}

// ---------------- kernel 2: LSE-weighted combine over R*NWIN ----------------
__global__ __launch_bounds__(128) void fd_reduce(
    const float* __restrict__ ws_m, const float* __restrict__ ws_l,
    const float* __restrict__ ws_o, float* __restrict__ out) {
  const int row = blockIdx.x;  // (b*HK + hk)*G + g
  const int g = row % G_;
  const int hk = (row / G_) % HK_;
  const int b = row / (G_ * HK_);
  const int d = threadIdx.x;
  const int hdr = hk * G_ + g;

  float mf = MNEG;
  for (int r = 0; r < R_; ++r)
    for (int s = 0; s < NWIN; ++s) {
      int idx = ((r * B_ + b) * NWIN + s) * 32 + hdr;
      mf = fmaxf(mf, ws_m[idx]);
    }
  float of = 0.f, lf = 0.f;
  for (int r = 0; r < R_; ++r)
    for (int s = 0; s < NWIN; ++s) {
      int idx = ((r * B_ + b) * NWIN + s) * 32 + hdr;
      float wt = exp2f(ws_m[idx] - mf);  // inactive -> 0
      of += wt * ws_o[(size_t)idx * D_ + d];
      lf += wt * ws_l[idx];
    }
  out[(size_t)(b * HQ_ + hk * G_ + g) * D_ + d] = of / lf;
}

// ---------------- fallback: monolithic (tiny workspace) ----------------
__global__ __launch_bounds__(256) void fd_mono(
    const float* __restrict__ q, const float* __restrict__ kc,
    const float* __restrict__ vc, const int* __restrict__ lens,
    const int* __restrict__ bt, float* __restrict__ out) {
  const int hk = blockIdx.x % HK_;
  const int b = blockIdx.x / HK_;
  const int lane = threadIdx.x & 63;
  const int g = threadIdx.x >> 6;
  const int tg = lane >> 4;
  const int ds = (lane & 15) * 8;
  const unsigned dsb = ds * 4u + ((unsigned)hk << 9);

  float qf[8];
  {
    const f32x4* p =
        (const f32x4*)(q + (size_t)(b * HQ_ + hk * G_ + g) * D_ + ds);
    f32x4 a = p[0], c = p[1];
#pragma unroll
    for (int j = 0; j < 4; ++j) {
      qf[j] = a[j] * SC2;
      qf[4 + j] = c[j] * SC2;
    }
  }

  float m = MNEG, l = 0.f, acc[8];
#pragma unroll
  for (int j = 0; j < 8; ++j) acc[j] = 0.f;

  for (int r = 0; r < R_; ++r) {
    int kvlen = lens[r * B_ + b];
    if (kvlen < 0) kvlen = 0;
    if (kvlen > M_) kvlen = M_;
    const int* btrow = bt + (r * B_ + b) * M_;
    const char* kb = (const char*)(kc + (size_t)r * P_ * HKD);
    const char* vb = (const char*)(vc + (size_t)r * P_ * HKD);

#pragma unroll 1
    for (int t = 0; t < kvlen; t += 4) {
      const int ta = t + tg;
      const bool va = ta < kvlen;
      const unsigned oa = ((unsigned)clampP(btrow[va ? ta : 0]) << 12) + dsb;
      float ka[8], wa[8];
      load8b(kb, oa, ka);
      load8b(vb, oa, wa);

      float da = 0.f;
#pragma unroll
      for (int j = 0; j < 8; ++j) da += qf[j] * ka[j];
#pragma unroll
      for (int msk = 1; msk <= 8; msk <<= 1) da += __shfl_xor(da, msk);

      const float sa = va ? da : -INFINITY;
      const float mn = fmaxf(m, sa);
      const float sc = exp2f(m - mn);
      const float pa = exp2f(sa - mn);
      m = mn;
      l = l * sc + pa;
#pragma unroll
      for (int j = 0; j < 8; ++j) acc[j] = acc[j] * sc + pa * wa[j];
    }
  }

#pragma unroll
  for (int off = 16; off <= 32; off <<= 1) {
    const float mo = __shfl_xor(m, off);
    const float lo = __shfl_xor(l, off);
    float ao[8];
#pragma unroll
    for (int j = 0; j < 8; ++j) ao[j] = __shfl_xor(acc[j], off);
    const float mn = fmaxf(m, mo);
    const float se = exp2f(m - mn);
    const float so_ = exp2f(mo - mn);
    l = l * se + lo * so_;
#pragma unroll
    for (int j = 0; j < 8; ++j) acc[j] = acc[j] * se + ao[j] * so_;
    m = mn;
  }

  if (lane < 16) {
    float inv = (l > 0.f) ? 1.0f / l : 0.f;
#pragma unroll
    for (int j = 0; j < 8; ++j)
      out[(size_t)(b * HQ_ + hk * G_ + g) * D_ + ds + j] = acc[j] * inv;
  }
}

extern "C" void kernel_launch(void* const* d_in, const int* in_sizes, int n_in,
                              void* d_out, int out_size, void* d_ws,
                              size_t ws_size, hipStream_t stream) {
  const float* q = (const float*)d_in[0];
  const float* kc = (const float*)d_in[1];
  const float* vc = (const float*)d_in[2];
  const int* lens = (const int*)d_in[3];
  const int* bt = (const int*)d_in[4];
  float* out = (float*)d_out;

  const int nrec = R_ * B_ * NWIN;  // 1024 blocks
  const size_t need = (size_t)nrec * 32 * (size_t)(2 + D_) * sizeof(float);

  if (need <= ws_size) {
    float* ws_m = (float*)d_ws;
    float* ws_l = ws_m + (size_t)nrec * 32;
    float* ws_o = ws_l + (size_t)nrec * 32;
    fd_partial<<<nrec, 256, 0, stream>>>(q, kc, vc, lens, bt, ws_m, ws_l,
                                         ws_o);
    fd_reduce<<<B_ * HK_ * G_, 128, 0, stream>>>(ws_m, ws_l, ws_o, out);
  } else {
    fd_mono<<<B_ * HK_, 256, 0, stream>>>(q, kc, vc, lens, bt, out);
  }
}

// Round 17
// 112.389 us; speedup vs baseline: 1.1718x; 1.1718x over previous
//
#include <hip/hip_runtime.h>
#include <math.h>

// flash-decode, GQA paged KV. R=4, B=16, Hq=32, Hk=8 (G=4), D=128, P=8192,
// PAGE=1, M=2048. Storage (r7): q/k/v FLOAT32; lens/bt int32; out f32.
//
// Round 17: async global_load_lds pipeline. All prior rounds (r8-r16) pin at
// 1.7-2.2 TB/s because pending loads live in VGPRs -> ~3 KB/CU outstanding
// (Little's law). Here each wave runs a depth-3 pipeline of 4-token tiles
// staged via global_load_lds (counted s_waitcnt vmcnt(8), never 0) -> in-
// flight bytes live in the vmcnt queue, not registers. One independent wave
// per (r,b,hk,s) record, no barriers. Page offsets pre-cached in LDS so the
// hot loop's only VMEM is the counted stage stream.

typedef float f32x4 __attribute__((ext_vector_type(4)));

#define R_ 4
#define B_ 16
#define HQ_ 32
#define HK_ 8
#define G_ 4
#define D_ 128
#define P_ 8192
#define M_ 2048
#define HKD (HK_ * D_)
#define NS 8   // splits per (r,b,hk) -> 4096 wave-records
#define T_ 4   // tokens per tile (4 KB staged per tile)
#define DP 3   // pipeline depth (2 tiles always in flight)
#define WV 2   // waves per block (128 threads, 26 KB LDS)
#define SC2 (0.08838834764831845f * 1.4426950408889634f)  // scale * log2(e)
#define MNEG (-1.0e30f)

__device__ __forceinline__ int clampP(int p) {
  return p < 0 ? 0 : (p >= P_ ? P_ - 1 : p);
}

// ---------------- kernel 1: one wave per (r,b,hk,split) ----------------
__global__ __launch_bounds__(WV * 64) void fd_partial(
    const float* __restrict__ q, const float* __restrict__ kc,
    const float* __restrict__ vc, const int* __restrict__ lens,
    const int* __restrict__ bt, float* __restrict__ ws_m,
    float* __restrict__ ws_l, float* __restrict__ ws_o) {
  __shared__ unsigned s_pg[WV][256];
  __shared__ float s_k[WV][DP][T_ * D_];
  __shared__ float s_v[WV][DP][T_ * D_];

  const int lane = threadIdx.x & 63;
  const int w = threadIdx.x >> 6;
  const int gw = blockIdx.x * WV + w;  // record id
  const int s = gw & (NS - 1);
  const int hk = (gw >> 3) & (HK_ - 1);
  const int b = (gw >> 6) & (B_ - 1);
  const int r = gw >> 10;

  const int tg = lane >> 4;  // slot 0..3: one token of the tile
  const int dl = lane & 15;  // dim-chunk index

  int kvlen = lens[r * B_ + b];
  kvlen = kvlen < 0 ? 0 : (kvlen > M_ ? M_ : kvlen);
  const int chunk = (((kvlen + NS - 1) / NS) + T_ - 1) & ~(T_ - 1);
  const int t0 = s * chunk;
  int t1 = t0 + chunk;
  if (t1 > kvlen) t1 = kvlen;
  const int ct = t1 - t0;
  if (ct <= 0) {  // inactive record: sentinel + exit (no barriers anywhere)
    if (lane == 0) {
#pragma unroll
      for (int h = 0; h < G_; ++h) ws_m[gw * G_ + h] = MNEG;
    }
    return;
  }
  const int cm1 = ct - 1;
  const int nT = (ct + T_ - 1) >> 2;

  // q fragments: dims [dl*4, dl*4+4) and [64+dl*4, ...) (match LDS chunks
  // chosen for even bank spread), pre-scaled into log2 domain
  float qf[G_][8];
  {
    const float* qp = q + ((size_t)b * HQ_ + hk * G_) * D_;
#pragma unroll
    for (int h = 0; h < G_; ++h) {
      f32x4 a = *(const f32x4*)(qp + h * D_ + dl * 4);
      f32x4 c = *(const f32x4*)(qp + h * D_ + 64 + dl * 4);
#pragma unroll
      for (int j = 0; j < 4; ++j) {
        qf[h][j] = a[j] * SC2;
        qf[h][4 + j] = c[j] * SC2;
      }
    }
  }

  // phase 0: page byte-offsets for this wave's chunk into LDS (clamped fill)
  {
    const int* btrow = bt + (r * B_ + b) * M_ + t0;
#pragma unroll
    for (int t = 0; t < 256; t += 64) {
      const int idx = t + lane;
      const int tt = idx > cm1 ? cm1 : idx;
      s_pg[w][idx] = ((unsigned)clampP(btrow[tt])) << 12;
    }
  }

  const char* kb = (const char*)kc + ((size_t)r * P_) * 4096 + hk * 512;
  const char* vb = (const char*)vc + ((size_t)r * P_) * 4096 + hk * 512;
  const unsigned* pgw = s_pg[w];
  const unsigned lo16 = ((unsigned)(lane & 31)) << 4;

  float m[G_], l[G_], acc[G_][8];
#pragma unroll
  for (int h = 0; h < G_; ++h) {
    m[h] = MNEG;
    l[h] = 0.f;
#pragma unroll
    for (int j = 0; j < 8; ++j) acc[h][j] = 0.f;
  }

  // zero the vmem baseline so the counted-vmcnt invariant holds
  asm volatile("s_waitcnt vmcnt(0) lgkmcnt(0)" ::: "memory");

  // stage tile k into slot sl: exactly 4 global_load_lds (K0,V0,K1,V1).
  // token (2j + lane>>5) of the tile; LDS lands linearly: token u at u*512B.
  auto stage = [&](int k, int sl) {
#pragma unroll
    for (int j = 0; j < 2; ++j) {
      int tau = T_ * k + 2 * j + (lane >> 5);
      tau = tau > cm1 ? cm1 : tau;  // over-run tiles restage last token
      const unsigned pgo = pgw[tau];
      __builtin_amdgcn_global_load_lds((const float*)(kb + pgo + lo16),
                                       &s_k[w][sl][j * 256], 16, 0, 0);
      __builtin_amdgcn_global_load_lds((const float*)(vb + pgo + lo16),
                                       &s_v[w][sl][j * 256], 16, 0, 0);
    }
  };

  stage(0, 0);
  stage(1, 1);
  stage(2, 2);

  int sl = 0;
  for (int i = 0; i < nT; ++i) {
    // <=8 outstanding == stages i+1,i+2 -> tile i's 4 loads complete
    asm volatile("s_waitcnt vmcnt(8)" ::: "memory");
    __builtin_amdgcn_sched_barrier(0);

    const float* kp = &s_k[w][sl][tg * D_];
    const float* vp = &s_v[w][sl][tg * D_];
    float kr[8], vr[8];
    {
      f32x4 a = *(const f32x4*)(kp + dl * 4);
      f32x4 c = *(const f32x4*)(kp + 64 + dl * 4);
#pragma unroll
      for (int j = 0; j < 4; ++j) { kr[j] = a[j]; kr[4 + j] = c[j]; }
    }
    float d0 = 0.f, d1 = 0.f, d2 = 0.f, d3 = 0.f;
#pragma unroll
    for (int j = 0; j < 8; ++j) {
      d0 += qf[0][j] * kr[j];
      d1 += qf[1][j] * kr[j];
      d2 += qf[2][j] * kr[j];
      d3 += qf[3][j] * kr[j];
    }
#pragma unroll
    for (int msk = 1; msk <= 8; msk <<= 1) {
      d0 += __shfl_xor(d0, msk);
      d1 += __shfl_xor(d1, msk);
      d2 += __shfl_xor(d2, msk);
      d3 += __shfl_xor(d3, msk);
    }
    {
      f32x4 a = *(const f32x4*)(vp + dl * 4);
      f32x4 c = *(const f32x4*)(vp + 64 + dl * 4);
#pragma unroll
      for (int j = 0; j < 4; ++j) { vr[j] = a[j]; vr[4 + j] = c[j]; }
    }
    const bool valid = (T_ * i + tg) < ct;
    float sH[G_];
    sH[0] = valid ? d0 : -INFINITY;
    sH[1] = valid ? d1 : -INFINITY;
    sH[2] = valid ? d2 : -INFINITY;
    sH[3] = valid ? d3 : -INFINITY;
#pragma unroll
    for (int h = 0; h < G_; ++h) {
      if (sH[h] > m[h]) {  // deferred rescale (exact; ~log(n) hits)
        const float rs = exp2f(m[h] - sH[h]);  // m=MNEG -> 0
        l[h] *= rs;
#pragma unroll
        for (int j = 0; j < 8; ++j) acc[h][j] *= rs;
        m[h] = sH[h];
      }
      const float p = exp2f(sH[h] - m[h]);  // invalid -> 0
      l[h] += p;
#pragma unroll
      for (int j = 0; j < 8; ++j) acc[h][j] += p * vr[j];
    }

    __builtin_amdgcn_sched_barrier(0);
    stage(i + DP, sl);  // refill the slot just consumed
    sl = (sl == DP - 1) ? 0 : sl + 1;
  }
  // drain: async LDS writes must land before workgroup LDS is reallocated
  asm volatile("s_waitcnt vmcnt(0)" ::: "memory");

  // merge the 4 token slots (xor 16, 32), per head
#pragma unroll
  for (int h = 0; h < G_; ++h) {
#pragma unroll
    for (int off = 16; off <= 32; off <<= 1) {
      const float mo = __shfl_xor(m[h], off);
      const float lo = __shfl_xor(l[h], off);
      float ao[8];
#pragma unroll
      for (int j = 0; j < 8; ++j) ao[j] = __shfl_xor(acc[h][j], off);
      const float mn = fmaxf(m[h], mo);
      const float se = exp2f(m[h] - mn);
      const float so_ = exp2f(mo - mn);
      l[h] = l[h] * se + lo * so_;
#pragma unroll
      for (int j = 0; j < 8; ++j) acc[h][j] = acc[h][j] * se + ao[j] * so_;
      m[h] = mn;
    }
  }

  if (tg == 0) {  // lanes 0-15: write dim chunks dl*4 and 64+dl*4
#pragma unroll
    for (int h = 0; h < G_; ++h) {
      float* wp = ws_o + ((size_t)gw * G_ + h) * D_;
      f32x4 a, c;
#pragma unroll
      for (int j = 0; j < 4; ++j) { a[j] = acc[h][j]; c[j] = acc[h][4 + j]; }
      *(f32x4*)(wp + dl * 4) = a;
      *(f32x4*)(wp + 64 + dl * 4) = c;
    }
  }
  if (lane == 0) {
#pragma unroll
    for (int h = 0; h < G_; ++h) {
      ws_m[gw * G_ + h] = m[h];  // log2-domain
      ws_l[gw * G_ + h] = l[h];
    }
  }
}

// ---------------- kernel 2: LSE-weighted combine over R*NS ----------------
__global__ __launch_bounds__(128) void fd_reduce(
    const float* __restrict__ ws_m, const float* __restrict__ ws_l,
    const float* __restrict__ ws_o, float* __restrict__ out) {
  const int row = blockIdx.x;  // (b*HK + hk)*G + g
  const int g = row % G_;
  const int hk = (row / G_) % HK_;
  const int b = row / (G_ * HK_);
  const int d = threadIdx.x;

  float mf = MNEG;
  for (int r = 0; r < R_; ++r)
    for (int s2 = 0; s2 < NS; ++s2) {
      int rec = ((r * B_ + b) * HK_ + hk) * NS + s2;
      mf = fmaxf(mf, ws_m[rec * G_ + g]);
    }
  float of = 0.f, lf = 0.f;
  for (int r = 0; r < R_; ++r)
    for (int s2 = 0; s2 < NS; ++s2) {
      int rec = ((r * B_ + b) * HK_ + hk) * NS + s2;
      float wt = exp2f(ws_m[rec * G_ + g] - mf);  // inactive -> 0
      of += wt * ws_o[(size_t)(rec * G_ + g) * D_ + d];
      lf += wt * ws_l[rec * G_ + g];
    }
  out[(size_t)(b * HQ_ + hk * G_ + g) * D_ + d] = of / lf;
}

// ---------------- fallback: monolithic (tiny workspace) ----------------
typedef float f32x4_ __attribute__((ext_vector_type(4)));
__device__ __forceinline__ void load8u(const float* __restrict__ ubase,
                                       unsigned boff, float o[8]) {
  const f32x4* p = (const f32x4*)((const char*)ubase + boff);
  f32x4 a = p[0];
  f32x4 b = p[1];
#pragma unroll
  for (int j = 0; j < 4; ++j) { o[j] = a[j]; o[4 + j] = b[j]; }
}

__global__ __launch_bounds__(256) void fd_mono(
    const float* __restrict__ q, const float* __restrict__ kc,
    const float* __restrict__ vc, const int* __restrict__ lens,
    const int* __restrict__ bt, float* __restrict__ out) {
  const int hk = blockIdx.x % HK_;
  const int b = blockIdx.x / HK_;
  const int lane = threadIdx.x & 63;
  const int g = threadIdx.x >> 6;
  const int tg = lane >> 4;
  const int ds = (lane & 15) * 8;
  const unsigned dsb = ds * 4u + ((unsigned)hk << 9);

  float qf[8];
  load8u(q + (size_t)(b * HQ_ + hk * G_ + g) * D_ + ds, 0u, qf);
#pragma unroll
  for (int j = 0; j < 8; ++j) qf[j] *= SC2;

  float m = MNEG, l = 0.f, acc[8];
#pragma unroll
  for (int j = 0; j < 8; ++j) acc[j] = 0.f;

  for (int r = 0; r < R_; ++r) {
    int kvlen = lens[r * B_ + b];
    if (kvlen < 0) kvlen = 0;
    if (kvlen > M_) kvlen = M_;
    const int* btrow = bt + (r * B_ + b) * M_;
    const float* kb = kc + (size_t)r * P_ * HKD;
    const float* vb = vc + (size_t)r * P_ * HKD;

#pragma unroll 1
    for (int t = 0; t < kvlen; t += 4) {
      const int ta = t + tg;
      const bool va = ta < kvlen;
      const unsigned oa = ((unsigned)clampP(btrow[va ? ta : 0]) << 12) + dsb;
      float ka[8], wa[8];
      load8u(kb, oa, ka);
      load8u(vb, oa, wa);

      float da = 0.f;
#pragma unroll
      for (int j = 0; j < 8; ++j) da += qf[j] * ka[j];
#pragma unroll
      for (int msk = 1; msk <= 8; msk <<= 1) da += __shfl_xor(da, msk);

      const float sa = va ? da : -INFINITY;
      const float mn = fmaxf(m, sa);
      const float sc = exp2f(m - mn);
      const float pa = exp2f(sa - mn);
      m = mn;
      l = l * sc + pa;
#pragma unroll
      for (int j = 0; j < 8; ++j) acc[j] = acc[j] * sc + pa * wa[j];
    }
  }

#pragma unroll
  for (int off = 16; off <= 32; off <<= 1) {
    const float mo = __shfl_xor(m, off);
    const float lo = __shfl_xor(l, off);
    float ao[8];
#pragma unroll
    for (int j = 0; j < 8; ++j) ao[j] = __shfl_xor(acc[j], off);
    const float mn = fmaxf(m, mo);
    const float se = exp2f(m - mn);
    const float so_ = exp2f(mo - mn);
    l = l * se + lo * so_;
#pragma unroll
    for (int j = 0; j < 8; ++j) acc[j] = acc[j] * se + ao[j] * so_;
    m = mn;
  }

  if (lane < 16) {
    float inv = (l > 0.f) ? 1.0f / l : 0.f;
#pragma unroll
    for (int j = 0; j < 8; ++j)
      out[(size_t)(b * HQ_ + hk * G_ + g) * D_ + ds + j] = acc[j] * inv;
  }
}

extern "C" void kernel_launch(void* const* d_in, const int* in_sizes, int n_in,
                              void* d_out, int out_size, void* d_ws,
                              size_t ws_size, hipStream_t stream) {
  const float* q = (const float*)d_in[0];
  const float* kc = (const float*)d_in[1];
  const float* vc = (const float*)d_in[2];
  const int* lens = (const int*)d_in[3];
  const int* bt = (const int*)d_in[4];
  float* out = (float*)d_out;

  const int nrec = R_ * B_ * HK_ * NS;  // 4096 wave-records
  const size_t need =
      (size_t)nrec * (size_t)(2 * G_ + G_ * D_) * sizeof(float);  // ~8.5 MB

  if (need <= ws_size) {
    float* ws_m = (float*)d_ws;
    float* ws_l = ws_m + (size_t)nrec * G_;
    float* ws_o = ws_l + (size_t)nrec * G_;
    fd_partial<<<nrec / WV, WV * 64, 0, stream>>>(q, kc, vc, lens, bt, ws_m,
                                                  ws_l, ws_o);
    fd_reduce<<<B_ * HK_ * G_, 128, 0, stream>>>(ws_m, ws_l, ws_o, out);
  } else {
    fd_mono<<<B_ * HK_, 256, 0, stream>>>(q, kc, vc, lens, bt, out);
  }
}

// Round 18
// 100.623 us; speedup vs baseline: 1.3088x; 1.1169x over previous
//
#include <hip/hip_runtime.h>
#include <math.h>

// flash-decode, GQA paged KV. R=4, B=16, Hq=32, Hk=8 (G=4), D=128, P=8192,
// PAGE=1, M=2048. Storage (r7): q/k/v FLOAT32; lens/bt int32; out f32.
//
// Round 18: PAGE-ORDER traversal. r8-r17 (10 structures) all pin at
// 1.7-2.2 TB/s: random-order 512B-4KB requests kill DRAM row locality.
// Softmax is order-invariant, so fd_compact counting-sorts each (r,b)'s
// block table by page (256 buckets of 32 pages, 8 range-segments padded
// to 64), and fd_partial (r13's proven body, unchanged) walks pages in
// ascending order with range-id slowest in blockIdx -> all resident
// blocks sweep a few compact address bands together.

typedef float f32x4 __attribute__((ext_vector_type(4)));

#define R_ 4
#define B_ 16
#define HQ_ 32
#define HK_ 8
#define G_ 4
#define D_ 128
#define P_ 8192
#define M_ 2048
#define HKD (HK_ * D_)
#define NR 8      // page-ranges per (r,b): pages [s*1024, s*1024+1024)
#define NBK 256   // sort buckets (page >> 5): 32 pages = 128 KB granule
#define PROW 2560 // padded row capacity (2048 + 8*64)
#define SC2 (0.08838834764831845f * 1.4426950408889634f)  // scale * log2(e)
#define MNEG (-1.0e30f)

__device__ __forceinline__ int clampP(int p) {
  return p < 0 ? 0 : (p >= P_ ? P_ - 1 : p);
}

// ---------- kernel 0: per-(r,b) counting sort of block_table ----------
__global__ __launch_bounds__(256) void fd_compact(
    const int* __restrict__ lens, const int* __restrict__ bt,
    unsigned* __restrict__ ws_pages, int* __restrict__ ws_meta) {
  __shared__ int hist[NBK];
  __shared__ int cur[NBK];
  __shared__ int rstart[NR + 1], rcnt[NR];
  const int rb = blockIdx.x;
  const int tid = threadIdx.x;
  int kvlen = lens[rb];
  kvlen = kvlen < 0 ? 0 : (kvlen > M_ ? M_ : kvlen);
  const int* btrow = bt + rb * M_;

  for (int i = tid; i < NBK; i += 256) hist[i] = 0;
  __syncthreads();
  for (int t = tid; t < kvlen; t += 256)
    atomicAdd(&hist[clampP(btrow[t]) >> 5], 1);
  __syncthreads();
  if (tid == 0) {
    int pos = 0;
    for (int s = 0; s < NR; ++s) {
      rstart[s] = pos;
      int n = 0;
      for (int j = 0; j < NBK / NR; ++j) {
        cur[s * (NBK / NR) + j] = pos + n;
        n += hist[s * (NBK / NR) + j];
      }
      rcnt[s] = n;
      pos += (n + 63) & ~63;  // range starts 64-aligned
    }
    rstart[NR] = pos;
  }
  __syncthreads();
  unsigned* prow = ws_pages + (size_t)rb * PROW;
  for (int t = tid; t < kvlen; t += 256) {
    const int p = clampP(btrow[t]);
    const int d = atomicAdd(&cur[p >> 5], 1);
    prow[d] = ((unsigned)p) << 12;  // byte offset of the page
  }
  __syncthreads();
  for (int s = 0; s < NR; ++s) {  // pad with a valid in-range page
    const int from = rstart[s] + rcnt[s];
    const int to = rstart[s + 1];
    for (int i = from + tid; i < to; i += 256)
      prow[i] = ((unsigned)(s * (P_ / NR))) << 12;
  }
  if (tid < NR) {
    ws_meta[rb * 2 * NR + tid * 2] = rstart[tid];
    ws_meta[rb * 2 * NR + tid * 2 + 1] = rcnt[tid];
  }
}

// ---------- kernel 1: block = (range, r, b, hk); r13 body ----------
__global__ __launch_bounds__(256) void fd_partial(
    const float* __restrict__ q, const float* __restrict__ kc,
    const float* __restrict__ vc, const unsigned* __restrict__ ws_pages,
    const int* __restrict__ ws_meta, float* __restrict__ ws_m,
    float* __restrict__ ws_l, float* __restrict__ ws_o) {
  const int bid = blockIdx.x;
  const int s = bid >> 9;  // range id, SLOWEST -> ranges run in order
  const int rbh = bid & 511;
  const int hk = rbh & (HK_ - 1);
  const int rb = rbh >> 3;  // r*B + b
  const int b = rb & (B_ - 1);
  const int r = rb >> 4;
  const int rec = bid;

  const int lane = threadIdx.x & 63;
  const int w = threadIdx.x >> 6;   // wave -> 16-token strip per 64-window
  const int tg = lane >> 4;         // slot 0..3: 4 tokens each
  const int ds = (lane & 15) * 8;   // dim slice [ds, ds+8)
  const unsigned dsb = ds * 4u;

  const int start = ws_meta[rb * 2 * NR + s * 2];
  const int n = ws_meta[rb * 2 * NR + s * 2 + 1];
  if (n <= 0) {  // empty range (block-uniform)
    if (lane == 0) ws_m[rec * G_ + w] = MNEG;
    return;
  }

  // q fragments for all 4 heads, pre-scaled into log2 domain
  float qf[G_][8];
  {
    const float* qp = q + (size_t)(b * HQ_ + hk * G_) * D_ + ds;
#pragma unroll
    for (int h = 0; h < G_; ++h) {
      const f32x4* p = (const f32x4*)(qp + h * D_);
      f32x4 a = p[0], c = p[1];
#pragma unroll
      for (int j = 0; j < 4; ++j) {
        qf[h][j] = a[j] * SC2;
        qf[h][4 + j] = c[j] * SC2;
      }
    }
  }

  const unsigned* plist = ws_pages + (size_t)rb * PROW + start;
  const float* kb = kc + (size_t)r * P_ * HKD + (size_t)hk * D_;
  const float* vb = vc + (size_t)r * P_ * HKD + (size_t)hk * D_;

  float m[G_], l[G_], acc[G_][8];
#pragma unroll
  for (int h = 0; h < G_; ++h) {
    m[h] = MNEG;
    l[h] = 0.f;
#pragma unroll
    for (int j = 0; j < 8; ++j) acc[h][j] = 0.f;
  }

  const int nIt = (n + 63) >> 6;
  const int sbase = w * 16 + tg * 4;  // 4-aligned; start is 64-aligned

  uint4 pgN = *(const uint4*)(plist + sbase);

#pragma unroll 1
  for (int i = 0; i < nIt; ++i) {
    const uint4 pg = pgN;
    if (i + 1 < nIt) pgN = *(const uint4*)(plist + sbase + (i + 1) * 64);
    const unsigned o0 = pg.x + dsb;
    const unsigned o1 = pg.y + dsb;
    const unsigned o2 = pg.z + dsb;
    const unsigned o3 = pg.w + dsb;

    float k0[8], k1[8], k2[8], k3[8], v0[8], v1[8], v2[8], v3[8];
    {
      const char* kcb = (const char*)kb;
      const char* vcb = (const char*)vb;
      const f32x4* p;
      p = (const f32x4*)(kcb + o0);
#pragma unroll
      for (int j = 0; j < 4; ++j) { k0[j] = p[0][j]; k0[4 + j] = p[1][j]; }
      p = (const f32x4*)(kcb + o1);
#pragma unroll
      for (int j = 0; j < 4; ++j) { k1[j] = p[0][j]; k1[4 + j] = p[1][j]; }
      p = (const f32x4*)(kcb + o2);
#pragma unroll
      for (int j = 0; j < 4; ++j) { k2[j] = p[0][j]; k2[4 + j] = p[1][j]; }
      p = (const f32x4*)(kcb + o3);
#pragma unroll
      for (int j = 0; j < 4; ++j) { k3[j] = p[0][j]; k3[4 + j] = p[1][j]; }
      p = (const f32x4*)(vcb + o0);
#pragma unroll
      for (int j = 0; j < 4; ++j) { v0[j] = p[0][j]; v0[4 + j] = p[1][j]; }
      p = (const f32x4*)(vcb + o1);
#pragma unroll
      for (int j = 0; j < 4; ++j) { v1[j] = p[0][j]; v1[4 + j] = p[1][j]; }
      p = (const f32x4*)(vcb + o2);
#pragma unroll
      for (int j = 0; j < 4; ++j) { v2[j] = p[0][j]; v2[4 + j] = p[1][j]; }
      p = (const f32x4*)(vcb + o3);
#pragma unroll
      for (int j = 0; j < 4; ++j) { v3[j] = p[0][j]; v3[4 + j] = p[1][j]; }
    }

    float d0[G_], d1[G_], d2[G_], d3[G_];
#pragma unroll
    for (int h = 0; h < G_; ++h) {
      float a0 = 0.f, a1 = 0.f, a2 = 0.f, a3 = 0.f;
#pragma unroll
      for (int j = 0; j < 8; ++j) {
        a0 += qf[h][j] * k0[j];
        a1 += qf[h][j] * k1[j];
        a2 += qf[h][j] * k2[j];
        a3 += qf[h][j] * k3[j];
      }
      d0[h] = a0; d1[h] = a1; d2[h] = a2; d3[h] = a3;
    }
#pragma unroll
    for (int msk = 1; msk <= 8; msk <<= 1) {
#pragma unroll
      for (int h = 0; h < G_; ++h) {
        d0[h] += __shfl_xor(d0[h], msk);
        d1[h] += __shfl_xor(d1[h], msk);
        d2[h] += __shfl_xor(d2[h], msk);
        d3[h] += __shfl_xor(d3[h], msk);
      }
    }

    const int tb = sbase + i * 64;  // index into the compacted list
    const bool va0 = tb < n;
    const bool va1 = tb + 1 < n;
    const bool va2 = tb + 2 < n;
    const bool va3 = tb + 3 < n;
#pragma unroll
    for (int h = 0; h < G_; ++h) {
      const float s0 = va0 ? d0[h] : -INFINITY;
      const float s1 = va1 ? d1[h] : -INFINITY;
      const float s2 = va2 ? d2[h] : -INFINITY;
      const float s3 = va3 ? d3[h] : -INFINITY;
      const float mt = fmaxf(fmaxf(s0, s1), fmaxf(s2, s3));
      const float mn = fmaxf(m[h], mt);   // finite always (>= MNEG)
      const float sc = exp2f(m[h] - mn);  // branchless, no NaN
      const float p0 = exp2f(s0 - mn);    // -inf -> 0
      const float p1 = exp2f(s1 - mn);
      const float p2 = exp2f(s2 - mn);
      const float p3 = exp2f(s3 - mn);
      m[h] = mn;
      l[h] = l[h] * sc + (p0 + p1) + (p2 + p3);
#pragma unroll
      for (int j = 0; j < 8; ++j)
        acc[h][j] = acc[h][j] * sc + p0 * v0[j] + p1 * v1[j] + p2 * v2[j] +
                    p3 * v3[j];
    }
  }

  // merge the 4 token slots (xor 16, 32), per head — branchless
#pragma unroll
  for (int h = 0; h < G_; ++h) {
#pragma unroll
    for (int off = 16; off <= 32; off <<= 1) {
      const float mo = __shfl_xor(m[h], off);
      const float lo = __shfl_xor(l[h], off);
      float ao[8];
#pragma unroll
      for (int j = 0; j < 8; ++j) ao[j] = __shfl_xor(acc[h][j], off);
      const float mn = fmaxf(m[h], mo);
      const float se = exp2f(m[h] - mn);
      const float so_ = exp2f(mo - mn);
      l[h] = l[h] * se + lo * so_;
#pragma unroll
      for (int j = 0; j < 8; ++j) acc[h][j] = acc[h][j] * se + ao[j] * so_;
      m[h] = mn;
    }
  }

  // cross-wave merge via LDS; wave w finalizes head g = w
  __shared__ float sm[4][G_], sl[4][G_], so[4][G_][D_ + 4];
  if (lane < 16) {
#pragma unroll
    for (int h = 0; h < G_; ++h) {
#pragma unroll
      for (int j = 0; j < 8; ++j) so[w][h][ds + j] = acc[h][j];
    }
    if (lane == 0) {
#pragma unroll
      for (int h = 0; h < G_; ++h) {
        sm[w][h] = m[h];
        sl[w][h] = l[h];
      }
    }
  }
  __syncthreads();

  const int g = w;
  const float mw0 = sm[0][g], mw1 = sm[1][g], mw2 = sm[2][g], mw3 = sm[3][g];
  const float mf = fmaxf(fmaxf(mw0, mw1), fmaxf(mw2, mw3));
  const float wt0 = exp2f(mw0 - mf);
  const float wt1 = exp2f(mw1 - mf);
  const float wt2 = exp2f(mw2 - mf);
  const float wt3 = exp2f(mw3 - mf);
  const float lf =
      wt0 * sl[0][g] + wt1 * sl[1][g] + wt2 * sl[2][g] + wt3 * sl[3][g];
  const float of0 = wt0 * so[0][g][lane] + wt1 * so[1][g][lane] +
                    wt2 * so[2][g][lane] + wt3 * so[3][g][lane];
  const float of1 = wt0 * so[0][g][lane + 64] + wt1 * so[1][g][lane + 64] +
                    wt2 * so[2][g][lane + 64] + wt3 * so[3][g][lane + 64];
  ws_o[((size_t)rec * G_ + g) * D_ + lane] = of0;
  ws_o[((size_t)rec * G_ + g) * D_ + lane + 64] = of1;
  if (lane == 0) {
    ws_m[rec * G_ + g] = mf;  // log2-domain
    ws_l[rec * G_ + g] = lf;
  }
}

// ---------- kernel 2: LSE-weighted combine over R_*NR records ----------
__global__ __launch_bounds__(128) void fd_reduce(
    const float* __restrict__ ws_m, const float* __restrict__ ws_l,
    const float* __restrict__ ws_o, float* __restrict__ out) {
  const int row = blockIdx.x;  // (b*HK + hk)*G + g
  const int g = row % G_;
  const int hk = (row / G_) % HK_;
  const int b = row / (G_ * HK_);
  const int d = threadIdx.x;

  float mf = MNEG;
  for (int r = 0; r < R_; ++r)
    for (int s = 0; s < NR; ++s) {
      const int rec = s * 512 + (r * B_ + b) * HK_ + hk;
      mf = fmaxf(mf, ws_m[rec * G_ + g]);
    }
  float of = 0.f, lf = 0.f;
  for (int r = 0; r < R_; ++r)
    for (int s = 0; s < NR; ++s) {
      const int rec = s * 512 + (r * B_ + b) * HK_ + hk;
      const float wt = exp2f(ws_m[rec * G_ + g] - mf);  // empty -> 0
      of += wt * ws_o[((size_t)rec * G_ + g) * D_ + d];
      lf += wt * ws_l[rec * G_ + g];
    }
  out[(size_t)(b * HQ_ + hk * G_ + g) * D_ + d] = of / lf;
}

// ---------------- fallback: monolithic (tiny workspace) ----------------
__device__ __forceinline__ void load8u(const float* __restrict__ ubase,
                                       unsigned boff, float o[8]) {
  const f32x4* p = (const f32x4*)((const char*)ubase + boff);
  f32x4 a = p[0];
  f32x4 b = p[1];
#pragma unroll
  for (int j = 0; j < 4; ++j) { o[j] = a[j]; o[4 + j] = b[j]; }
}

__global__ __launch_bounds__(256) void fd_mono(
    const float* __restrict__ q, const float* __restrict__ kc,
    const float* __restrict__ vc, const int* __restrict__ lens,
    const int* __restrict__ bt, float* __restrict__ out) {
  const int hk = blockIdx.x % HK_;
  const int b = blockIdx.x / HK_;
  const int lane = threadIdx.x & 63;
  const int g = threadIdx.x >> 6;
  const int tg = lane >> 4;
  const int ds = (lane & 15) * 8;
  const unsigned dsb = ds * 4u;

  float qf[8];
  load8u(q + (size_t)(b * HQ_ + hk * G_ + g) * D_ + ds, 0u, qf);
#pragma unroll
  for (int j = 0; j < 8; ++j) qf[j] *= SC2;

  float m = MNEG, l = 0.f, acc[8];
#pragma unroll
  for (int j = 0; j < 8; ++j) acc[j] = 0.f;

  for (int r = 0; r < R_; ++r) {
    int kvlen = lens[r * B_ + b];
    if (kvlen < 0) kvlen = 0;
    if (kvlen > M_) kvlen = M_;
    const int* btrow = bt + (r * B_ + b) * M_;
    const float* kb = kc + (size_t)r * P_ * HKD + (size_t)hk * D_;
    const float* vb = vc + (size_t)r * P_ * HKD + (size_t)hk * D_;

#pragma unroll 1
    for (int t = 0; t < kvlen; t += 4) {
      const int ta = t + tg;
      const bool va = ta < kvlen;
      const unsigned oa = ((unsigned)clampP(btrow[va ? ta : 0]) << 12) + dsb;
      float ka[8], wa[8];
      load8u(kb, oa, ka);
      load8u(vb, oa, wa);

      float da = 0.f;
#pragma unroll
      for (int j = 0; j < 8; ++j) da += qf[j] * ka[j];
#pragma unroll
      for (int msk = 1; msk <= 8; msk <<= 1) da += __shfl_xor(da, msk);

      const float sa = va ? da : -INFINITY;
      const float mn = fmaxf(m, sa);
      const float sc = exp2f(m - mn);
      const float pa = exp2f(sa - mn);
      m = mn;
      l = l * sc + pa;
#pragma unroll
      for (int j = 0; j < 8; ++j) acc[j] = acc[j] * sc + pa * wa[j];
    }
  }

#pragma unroll
  for (int off = 16; off <= 32; off <<= 1) {
    const float mo = __shfl_xor(m, off);
    const float lo = __shfl_xor(l, off);
    float ao[8];
#pragma unroll
    for (int j = 0; j < 8; ++j) ao[j] = __shfl_xor(acc[j], off);
    const float mn = fmaxf(m, mo);
    const float se = exp2f(m - mn);
    const float so_ = exp2f(mo - mn);
    l = l * se + lo * so_;
#pragma unroll
    for (int j = 0; j < 8; ++j) acc[j] = acc[j] * se + ao[j] * so_;
    m = mn;
  }

  if (lane < 16) {
    float inv = (l > 0.f) ? 1.0f / l : 0.f;
#pragma unroll
    for (int j = 0; j < 8; ++j)
      out[(size_t)(b * HQ_ + hk * G_ + g) * D_ + ds + j] = acc[j] * inv;
  }
}

extern "C" void kernel_launch(void* const* d_in, const int* in_sizes, int n_in,
                              void* d_out, int out_size, void* d_ws,
                              size_t ws_size, hipStream_t stream) {
  const float* q = (const float*)d_in[0];
  const float* kc = (const float*)d_in[1];
  const float* vc = (const float*)d_in[2];
  const int* lens = (const int*)d_in[3];
  const int* bt = (const int*)d_in[4];
  float* out = (float*)d_out;

  const int nrec = NR * R_ * B_ * HK_;  // 4096 records
  const size_t sz_pages = (size_t)R_ * B_ * PROW * 4;          // 640 KB
  const size_t sz_meta = (size_t)R_ * B_ * 2 * NR * 4;         // 4 KB
  const size_t sz_ml = (size_t)nrec * G_ * 4;                  // 64 KB each
  const size_t sz_o = (size_t)nrec * G_ * D_ * 4;              // 8 MB
  const size_t need = sz_pages + sz_meta + 2 * sz_ml + sz_o;

  if (need <= ws_size) {
    char* p = (char*)d_ws;
    unsigned* ws_pages = (unsigned*)p;          p += sz_pages;
    int* ws_meta = (int*)p;                     p += sz_meta;
    float* ws_m = (float*)p;                    p += sz_ml;
    float* ws_l = (float*)p;                    p += sz_ml;
    float* ws_o = (float*)p;
    fd_compact<<<R_ * B_, 256, 0, stream>>>(lens, bt, ws_pages, ws_meta);
    fd_partial<<<nrec, 256, 0, stream>>>(q, kc, vc, ws_pages, ws_meta, ws_m,
                                         ws_l, ws_o);
    fd_reduce<<<B_ * HK_ * G_, 128, 0, stream>>>(ws_m, ws_l, ws_o, out);
  } else {
    fd_mono<<<B_ * HK_, 256, 0, stream>>>(q, kc, vc, lens, bt, out);
  }
}